// Round 16
// baseline (1930.286 us; speedup 1.0000x reference)
//
#include <hip/hip_runtime.h>

#define T_SEQ 2048
#define NBATCH 64
#define DIM 128      // SEQ_LEN
#define HID 128      // HIDDEN
#define G4 512       // 4*HID
#define GRP 16       // steps per load-batch group (scan)
#define TT 16        // timesteps per block (pre_mfma)
#define LOG2E 1.44269504088896f

typedef _Float16 h2v   __attribute__((ext_vector_type(2)));
typedef _Float16 f16x8 __attribute__((ext_vector_type(8)));
typedef float    f32x4 __attribute__((ext_vector_type(4)));

__device__ __forceinline__ unsigned pack2(float lo, float hi) {
    h2v v; v.x = (_Float16)lo; v.y = (_Float16)hi;
    return __builtin_bit_cast(unsigned, v);
}
__device__ __forceinline__ float dot2(unsigned a, unsigned b, float c) {
#if __has_builtin(__builtin_amdgcn_fdot2)
    return __builtin_amdgcn_fdot2(__builtin_bit_cast(h2v, a),
                                  __builtin_bit_cast(h2v, b), c, false);
#else
    h2v av = __builtin_bit_cast(h2v, a), bv = __builtin_bit_cast(h2v, b);
    c = fmaf((float)av.x, (float)bv.x, c);
    return fmaf((float)av.y, (float)bv.y, c);
#endif
}
__device__ __forceinline__ float rcp_(float x)  { return __builtin_amdgcn_rcpf(x); }
__device__ __forceinline__ float exp2_(float x) { return __builtin_amdgcn_exp2f(x); }
// DPP helpers (quad_perm)
template <int CTRL>
__device__ __forceinline__ float qmov(float v) {
    int r = __builtin_amdgcn_mov_dpp(__builtin_bit_cast(int, v), CTRL, 0xF, 0xF, true);
    return __builtin_bit_cast(float, r);
}
#define QP_XOR1 0xB1   // [1,0,3,2]
#define QP_XOR2 0x4E   // [2,3,0,1]
#define QP_B0   0x00
#define QP_B1   0x55
#define QP_B2   0xAA
#define QP_B3   0xFF

// barrier that drains ONLY lgkm (ds) — vm loads keep flowing across it
__device__ __forceinline__ void barrier_lgkm() {
    asm volatile("s_waitcnt lgkmcnt(0)\n\ts_barrier" ::: "memory");
    __builtin_amdgcn_sched_barrier(0);
}

// ---- prep: x->f16; pre-pack Wih A-fragments (scaled) and Whh scan-words; bias_s ----
__global__ __launch_bounds__(256) void prep(
    const float* __restrict__ x,      // [B][T][DIM]
    const float* __restrict__ Wih,    // [DIM][G4]
    const float* __restrict__ Whh,    // [HID][G4]
    const float* __restrict__ bias,   // [G4] gate-major
    _Float16* __restrict__ x16,       // [B][T][DIM]
    _Float16* __restrict__ aXf,       // [8w][4j][4ks][64l][8i] scaled f16
    unsigned* __restrict__ whh_pk,    // [g*16+i][512 tid] scaled packed pairs
    float* __restrict__ bias_s)       // [512] ch=4u+g, scaled
{
    const size_t gtid   = (size_t)blockIdx.x * blockDim.x + threadIdx.x;
    const size_t stride = (size_t)gridDim.x * blockDim.x;

    const size_t n_x2 = (size_t)NBATCH * T_SEQ * DIM / 2;
    for (size_t i = gtid; i < n_x2; i += stride) {
        float2 v = reinterpret_cast<const float2*>(x)[i];
        h2v p; p.x = (_Float16)v.x; p.y = (_Float16)v.y;
        reinterpret_cast<h2v*>(x16)[i] = p;
    }
    // Wih fragments: 65536 f16
    for (size_t n = gtid; n < 65536; n += stride) {
        int i  = (int)n & 7;
        int l  = ((int)n >> 3) & 63;
        int ks = ((int)n >> 9) & 3;
        int j  = ((int)n >> 11) & 3;
        int w  = (int)n >> 13;
        int col = l & 15, hi = l >> 4;
        int chr  = 16 * (4 * w + j) + col;
        int wcol = (chr & 3) * HID + (chr >> 2);
        float sc = ((chr & 3) == 2) ? -2.0f * LOG2E : -LOG2E;
        int k = ks * 32 + hi * 8 + i;
        aXf[n] = (_Float16)(Wih[(size_t)k * G4 + wcol] * sc);
    }
    // Whh packed words: 32768 (512-thread scan layout)
    for (size_t n = gtid; n < 32768; n += stride) {
        int tid = (int)n & 511;
        int gi  = (int)n >> 9;          // g*16+ii
        int g = gi >> 4, ii = gi & 15;
        int j = tid >> 2, q = tid & 3;
        int k0 = q * 32 + 2 * ii;
        float sc = (g == 2) ? -2.0f * LOG2E : -LOG2E;
        whh_pk[n] = pack2(Whh[(size_t)k0 * G4 + g * HID + j] * sc,
                          Whh[(size_t)(k0 + 1) * G4 + g * HID + j] * sc);
    }
    for (size_t n = gtid; n < 512; n += stride) {
        int gate = (int)n & 3, u = (int)n >> 2;
        float sc = (gate == 2) ? -2.0f * LOG2E : -LOG2E;
        bias_s[n] = bias[gate * HID + u] * sc;
    }
}

// ---- Phase 1 (MFMA): pre[lt][b][ch=4u+g] = f16 of scaled pre-activation ----
__global__ __launch_bounds__(512, 2) void pre_mfma(
    const _Float16* __restrict__ x16, // [B][T][DIM]
    const _Float16* __restrict__ aXf,
    const float* __restrict__ bias_s, // [512] scaled
    _Float16* __restrict__ pre,       // [tcnt][64][512]
    int t0)
{
    const int tid = threadIdx.x;
    const int w   = tid >> 6;
    const int l   = tid & 63;
    const int col = l & 15;
    const int hi  = l >> 4;
    const int bg  = blockIdx.x & 3;
    const int lt0 = (blockIdx.x >> 2) * TT;
    const int batch = bg * 16 + col;

    f16x8 aX[4][4];
    f32x4 bv[4];
    #pragma unroll
    for (int j = 0; j < 4; ++j) {
        #pragma unroll
        for (int ks = 0; ks < 4; ++ks)
            aX[j][ks] = *reinterpret_cast<const f16x8*>(
                aXf + (((size_t)(w * 4 + j) * 4 + ks) << 9) + l * 8);
        bv[j] = *reinterpret_cast<const f32x4*>(bias_s + 64 * w + 16 * j + 4 * hi);
    }

    const _Float16* xb_base = x16 + (size_t)batch * T_SEQ * DIM + hi * 8;

    for (int tt = 0; tt < TT; ++tt) {
        const int lt = lt0 + tt;
        const int t  = t0 + lt;
        f16x8 xf[4];
        #pragma unroll
        for (int ks = 0; ks < 4; ++ks)
            xf[ks] = *reinterpret_cast<const f16x8*>(
                xb_base + (size_t)t * DIM + ks * 32);
        #pragma unroll
        for (int j = 0; j < 4; ++j) {
            f32x4 acc = bv[j];
            #pragma unroll
            for (int ks = 0; ks < 4; ++ks)
                acc = __builtin_amdgcn_mfma_f32_16x16x32_f16(aX[j][ks], xf[ks], acc, 0, 0, 0);
            uint2 o;
            o.x = pack2(acc[0], acc[1]);
            o.y = pack2(acc[2], acc[3]);
            *reinterpret_cast<uint2*>(
                pre + ((size_t)lt * NBATCH + batch) * G4 + 16 * (4 * w + j) + 4 * hi) = o;
        }
    }
}

// ---- Phase 2: scan, TWO batches per block. grid.x = 32, block = 512:
// thread = (unit j=tid>>2, quarter q=tid&3); handles batches b0=2*blk, b1=b0+1
// with shared wpk. Per step-pair: one barrier; B's dot issue hides A's
// transcendental latency. state layout (floats): h[64*128] | c[64*128]
__global__ __launch_bounds__(512, 1) void lstm_scan(
    const _Float16* __restrict__ pre, // [tc][B][G4] ch=4u+g, scaled
    const unsigned* __restrict__ whh_pk, // [g*16+i][512]
    const float* __restrict__ h0,
    const float* __restrict__ c0,
    float* __restrict__ state,
    _Float16* __restrict__ trace,     // [B][T][HID]
    int t0, int tc)
{
    __shared__ __align__(16) _Float16 h_sh[2][2][HID];   // [buf][batch-half][unit]

    const int tid = threadIdx.x;
    const int j = tid >> 2;           // unit
    const int q = tid & 3;            // k-quarter / gate owner
    const int b0 = blockIdx.x * 2;
    const int b1 = b0 + 1;
    const bool q1 = (q & 1) != 0;
    const bool q2 = (q & 2) != 0;

    float* st_h = state;
    float* st_c = state + NBATCH * HID;

    // W_hh fragments (shared by both batches): 64 coalesced loads
    unsigned wpk[4][16];
    #pragma unroll
    for (int g = 0; g < 4; ++g)
        #pragma unroll
        for (int ii = 0; ii < 16; ++ii)
            wpk[g][ii] = whh_pk[(size_t)(g * 16 + ii) * 512 + tid];

    float cA, cB, hjA, hjB;
    if (t0 == 0) {
        hjA = h0[b0 * HID + j]; cA = c0[b0 * HID + j];
        hjB = h0[b1 * HID + j]; cB = c0[b1 * HID + j];
    } else {
        hjA = st_h[b0 * HID + j]; cA = st_c[b0 * HID + j];
        hjB = st_h[b1 * HID + j]; cB = st_c[b1 * HID + j];
    }
    if (q == 0) {
        h_sh[0][0][j] = (_Float16)hjA;
        h_sh[0][1][j] = (_Float16)hjB;
    }

    const size_t pstep = (size_t)NBATCH * G4;
    const _Float16* pbA = pre + (size_t)b0 * G4 + tid;
    const _Float16* pbB = pre + (size_t)b1 * G4 + tid;
    _Float16* tbA = trace + ((size_t)b0 * T_SEQ + t0) * HID + j;
    _Float16* tbB = trace + ((size_t)b1 * T_SEQ + t0) * HID + j;

    // ping-pong group buffers for both batches
    unsigned short pA0[GRP], pA1[GRP], pB0[GRP], pB1[GRP];
    #pragma unroll
    for (int s = 0; s < GRP; ++s) {
        pA0[s] = __builtin_bit_cast(unsigned short, pbA[(size_t)s * pstep]);
        pA1[s] = __builtin_bit_cast(unsigned short, pbB[(size_t)s * pstep]);
    }

    __syncthreads();

#define LOADG(P0, P1, TGN)                                                   \
    {                                                                        \
        const int tgl = (TGN);                                               \
        _Pragma("unroll")                                                    \
        for (int s = 0; s < GRP; ++s) {                                      \
            P0[s] = __builtin_bit_cast(unsigned short,                       \
                        pbA[(size_t)(tgl + s) * pstep]);                     \
            P1[s] = __builtin_bit_cast(unsigned short,                       \
                        pbB[(size_t)(tgl + s) * pstep]);                     \
        }                                                                    \
    }

#define GEMV(HP, A0, A1, A2, A3)                                             \
    {                                                                        \
        _Pragma("unroll")                                                    \
        for (int m = 0; m < 4; ++m) {                                        \
            uint4 hv = (HP)[m];                                              \
            A0 = dot2(hv.x, wpk[0][4 * m + 0], A0);                          \
            A1 = dot2(hv.x, wpk[1][4 * m + 0], A1);                          \
            A2 = dot2(hv.x, wpk[2][4 * m + 0], A2);                          \
            A3 = dot2(hv.x, wpk[3][4 * m + 0], A3);                          \
            A0 = dot2(hv.y, wpk[0][4 * m + 1], A0);                          \
            A1 = dot2(hv.y, wpk[1][4 * m + 1], A1);                          \
            A2 = dot2(hv.y, wpk[2][4 * m + 1], A2);                          \
            A3 = dot2(hv.y, wpk[3][4 * m + 1], A3);                          \
            A0 = dot2(hv.z, wpk[0][4 * m + 2], A0);                          \
            A1 = dot2(hv.z, wpk[1][4 * m + 2], A1);                          \
            A2 = dot2(hv.z, wpk[2][4 * m + 2], A2);                          \
            A3 = dot2(hv.z, wpk[3][4 * m + 2], A3);                          \
            A0 = dot2(hv.w, wpk[0][4 * m + 3], A0);                          \
            A1 = dot2(hv.w, wpk[1][4 * m + 3], A1);                          \
            A2 = dot2(hv.w, wpk[2][4 * m + 3], A2);                          \
            A3 = dot2(hv.w, wpk[3][4 * m + 3], A3);                          \
        }                                                                    \
    }

#define EPI(A0, A1, A2, A3, PRV, CV, HJ)                                     \
    float hn_;                                                               \
    {                                                                        \
        float t01  = q1 ? A1 : A0;                                           \
        float t01o = q1 ? A0 : A1;                                           \
        t01 += qmov<QP_XOR1>(t01o);                                          \
        float t23  = q1 ? A3 : A2;                                           \
        float t23o = q1 ? A2 : A3;                                           \
        t23 += qmov<QP_XOR1>(t23o);                                          \
        float tq  = q2 ? t23 : t01;                                          \
        float tqo = q2 ? t01 : t23;                                          \
        tq += qmov<QP_XOR2>(tqo);                                            \
        tq += (float)__builtin_bit_cast(_Float16, PRV);                      \
        float v = rcp_(1.0f + exp2_(tq));                                    \
        float gi = qmov<QP_B0>(v);                                           \
        float gf = qmov<QP_B1>(v);                                           \
        float vg = qmov<QP_B2>(v);                                           \
        float go = qmov<QP_B3>(v);                                           \
        CV = fmaf(gf, CV, fmaf(gi + gi, vg, -gi));                           \
        float vc = rcp_(1.0f + exp2_(-2.0f * LOG2E * CV));                   \
        hn_ = fmaf(go + go, vc, -go);                                        \
        HJ = hn_;                                                            \
    }

#define STEP16(P0, P1, TG)                                                   \
    _Pragma("unroll")                                                        \
    for (int ss = 0; ss < GRP; ++ss) {                                       \
        const int cur = ss & 1;                                              \
        const uint4* hpA = reinterpret_cast<const uint4*>(&h_sh[cur][0][q * 32]); \
        const uint4* hpB = reinterpret_cast<const uint4*>(&h_sh[cur][1][q * 32]); \
        float a0 = 0.f, a1 = 0.f, a2 = 0.f, a3 = 0.f;                        \
        float e0 = 0.f, e1 = 0.f, e2 = 0.f, e3 = 0.f;                        \
        GEMV(hpA, a0, a1, a2, a3);                                           \
        GEMV(hpB, e0, e1, e2, e3);                                           \
        { EPI(a0, a1, a2, a3, P0[ss], cA, hjA)                               \
          if (q == 0) {                                                      \
              _Float16 h16 = (_Float16)hn_;                                  \
              h_sh[cur ^ 1][0][j] = h16;                                     \
              tbA[(size_t)((TG) + ss) * HID] = h16;                          \
          } }                                                                \
        { EPI(e0, e1, e2, e3, P1[ss], cB, hjB)                               \
          if (q == 0) {                                                      \
              _Float16 h16 = (_Float16)hn_;                                  \
              h_sh[cur ^ 1][1][j] = h16;                                     \
              tbB[(size_t)((TG) + ss) * HID] = h16;                          \
          } }                                                                \
        barrier_lgkm();                                                      \
    }

    for (int tg = 0; tg < tc; tg += 2 * GRP) {
        LOADG(pB0, pB1, tg + GRP);                       // next group (in range)
        STEP16(pA0, pA1, tg);
        const int tga = (tg + 2 * GRP < tc) ? tg + 2 * GRP : tg;  // clamp
        LOADG(pA0, pA1, tga);
        STEP16(pB0, pB1, tg + GRP);
    }
#undef LOADG
#undef GEMV
#undef EPI
#undef STEP16

    if (t0 + tc < T_SEQ) {
        if (q == 0) {
            st_h[b0 * HID + j] = hjA; st_c[b0 * HID + j] = cA;
            st_h[b1 * HID + j] = hjB; st_c[b1 * HID + j] = cB;
        }
    }
}

// ---- Phase 3a: FC partials. grid (64, 4): block (b, ck) covers T/4 of the t-range.
__global__ __launch_bounds__(256) void fc_part(
    const _Float16* __restrict__ trace,  // [B][T][HID]
    const float* __restrict__ fcw,       // [2][T*HID]
    float* __restrict__ part)            // [B][4][2]
{
    __shared__ float red[4][2];
    const int b = blockIdx.x, ck = blockIdx.y, tid = threadIdx.x;
    const int n4 = T_SEQ * HID / 4;
    const int base = ck * n4;
    const _Float16* tbase = trace + (size_t)b * (T_SEQ * HID) + base;
    const float* w0 = fcw + base;
    const float* w1 = fcw + (size_t)T_SEQ * HID + base;

    float s0 = 0.f, s1 = 0.f;
    for (int i = tid * 8; i < n4; i += 256 * 8) {
        uint4 tv = *reinterpret_cast<const uint4*>(tbase + i);
        float wa0[8], wa1[8];
        *reinterpret_cast<float4*>(&wa0[0]) = *reinterpret_cast<const float4*>(w0 + i);
        *reinterpret_cast<float4*>(&wa0[4]) = *reinterpret_cast<const float4*>(w0 + i + 4);
        *reinterpret_cast<float4*>(&wa1[0]) = *reinterpret_cast<const float4*>(w1 + i);
        *reinterpret_cast<float4*>(&wa1[4]) = *reinterpret_cast<const float4*>(w1 + i + 4);
        const unsigned* tw = reinterpret_cast<const unsigned*>(&tv);
        #pragma unroll
        for (int e = 0; e < 4; ++e) {
            h2v hh = __builtin_bit_cast(h2v, tw[e]);
            float hx = (float)hh.x, hy = (float)hh.y;
            s0 = fmaf(hx, wa0[2 * e], s0);
            s0 = fmaf(hy, wa0[2 * e + 1], s0);
            s1 = fmaf(hx, wa1[2 * e], s1);
            s1 = fmaf(hy, wa1[2 * e + 1], s1);
        }
    }
    #pragma unroll
    for (int d = 32; d >= 1; d >>= 1) {
        s0 += __shfl_xor(s0, d);
        s1 += __shfl_xor(s1, d);
    }
    const int w = tid >> 6;
    if ((tid & 63) == 0) { red[w][0] = s0; red[w][1] = s1; }
    __syncthreads();
    if (tid < 2) {
        part[(b * 4 + ck) * 2 + tid] =
            red[0][tid] + red[1][tid] + red[2][tid] + red[3][tid];
    }
}

// ---- Phase 3b: finish ----
__global__ __launch_bounds__(128) void fc_fin(
    const float* __restrict__ part,      // [B][4][2]
    const float* __restrict__ fcb,
    float* __restrict__ out)             // [B][2]
{
    const int tid = threadIdx.x;
    const int b = tid >> 1, o = tid & 1;
    float v = part[(b * 4 + 0) * 2 + o] + part[(b * 4 + 1) * 2 + o]
            + part[(b * 4 + 2) * 2 + o] + part[(b * 4 + 3) * 2 + o];
    out[b * 2 + o] = v + fcb[o];
}

extern "C" void kernel_launch(void* const* d_in, const int* in_sizes, int n_in,
                              void* d_out, int out_size, void* d_ws, size_t ws_size,
                              hipStream_t stream) {
    const float* x    = (const float*)d_in[0];
    const float* h0   = (const float*)d_in[1];
    const float* c0   = (const float*)d_in[2];
    const float* Wih  = (const float*)d_in[3];
    const float* Whh  = (const float*)d_in[4];
    const float* bias = (const float*)d_in[5];
    const float* fcw  = (const float*)d_in[6];
    const float* fcb  = (const float*)d_in[7];
    float* out = (float*)d_out;

    // ws layout (bytes): x16 32MB | trace 32MB | state 64KB | part 2KB |
    //                    aXf 128KB | whh_pk 128KB | bias_s 2KB | pre (rest)
    char* wsb = (char*)d_ws;
    const size_t X = (size_t)NBATCH * T_SEQ * DIM * 2;
    _Float16* x16    = (_Float16*)wsb;
    _Float16* trace  = (_Float16*)(wsb + X);
    float*    state  = (float*)(wsb + 2 * X);
    float*    part   = (float*)(wsb + 2 * X + 65536);
    _Float16* aXf    = (_Float16*)(wsb + 2 * X + 65536 + 2048);
    unsigned* whh_pk = (unsigned*)(wsb + 2 * X + 65536 + 2048 + 131072);
    float*    bias_s = (float*)(wsb + 2 * X + 65536 + 2048 + 2 * 131072);
    _Float16* pre    = (_Float16*)(wsb + 2 * X + 65536 + 2048 + 2 * 131072 + 2048);

    const size_t head = 2 * X + 65536 + 2048 + 2 * 131072 + 2048;
    const size_t per_t_bytes = (size_t)NBATCH * G4 * sizeof(_Float16);
    size_t avail = (ws_size > head) ? ws_size - head : 0;
    int Tc = (int)(avail / per_t_bytes);
    Tc &= ~(2 * GRP - 1);           // multiple of 32 (ping-pong; TT=16 divides)
    if (Tc < 2 * GRP) Tc = 2 * GRP; // fallback (ws known >= ~200 MB from R12)
    if (Tc > T_SEQ) Tc = T_SEQ;

    prep<<<512, 256, 0, stream>>>(x, Wih, Whh, bias, x16, aXf, whh_pk, bias_s);
    for (int t0 = 0; t0 < T_SEQ; t0 += Tc) {
        int tc = (t0 + Tc <= T_SEQ) ? Tc : (T_SEQ - t0);   // multiple of 32
        pre_mfma<<<(tc / TT) * 4, 512, 0, stream>>>(x16, aXf, bias_s, pre, t0);
        lstm_scan<<<32, 512, 0, stream>>>(pre, whh_pk, h0, c0, state, trace, t0, tc);
    }
    fc_part<<<dim3(64, 4), 256, 0, stream>>>(trace, fcw, part);
    fc_fin<<<1, 128, 0, stream>>>(part, fcb, out);
}

// Round 17
// 1074.866 us; speedup vs baseline: 1.7958x; 1.7958x over previous
//
#include <hip/hip_runtime.h>

#define T_SEQ 2048
#define NBATCH 64
#define DIM 128      // SEQ_LEN
#define HID 128      // HIDDEN
#define G4 512       // 4*HID
#define GRP 16       // steps per load-batch group (scan)
#define TT 16        // timesteps per block (pre_mfma)
#define LOG2E 1.44269504088896f

typedef _Float16 h2v   __attribute__((ext_vector_type(2)));
typedef _Float16 f16x8 __attribute__((ext_vector_type(8)));
typedef float    f32x4 __attribute__((ext_vector_type(4)));

__device__ __forceinline__ unsigned pack2(float lo, float hi) {
    h2v v; v.x = (_Float16)lo; v.y = (_Float16)hi;
    return __builtin_bit_cast(unsigned, v);
}
__device__ __forceinline__ float dot2(unsigned a, unsigned b, float c) {
#if __has_builtin(__builtin_amdgcn_fdot2)
    return __builtin_amdgcn_fdot2(__builtin_bit_cast(h2v, a),
                                  __builtin_bit_cast(h2v, b), c, false);
#else
    h2v av = __builtin_bit_cast(h2v, a), bv = __builtin_bit_cast(h2v, b);
    c = fmaf((float)av.x, (float)bv.x, c);
    return fmaf((float)av.y, (float)bv.y, c);
#endif
}
__device__ __forceinline__ float rcp_(float x)  { return __builtin_amdgcn_rcpf(x); }
__device__ __forceinline__ float exp2_(float x) { return __builtin_amdgcn_exp2f(x); }
// DPP helpers (quad_perm)
template <int CTRL>
__device__ __forceinline__ float qmov(float v) {
    int r = __builtin_amdgcn_mov_dpp(__builtin_bit_cast(int, v), CTRL, 0xF, 0xF, true);
    return __builtin_bit_cast(float, r);
}
#define QP_XOR1 0xB1   // [1,0,3,2]
#define QP_XOR2 0x4E   // [2,3,0,1]
#define QP_B0   0x00
#define QP_B1   0x55
#define QP_B2   0xAA
#define QP_B3   0xFF

// barrier that drains ONLY lgkm (ds) — vm loads keep flowing across it
__device__ __forceinline__ void barrier_lgkm() {
    asm volatile("s_waitcnt lgkmcnt(0)\n\ts_barrier" ::: "memory");
    __builtin_amdgcn_sched_barrier(0);
}

// ---- prep: x->f16; pre-pack Wih A-fragments (scaled) and Whh scan-words; bias_s ----
__global__ __launch_bounds__(256) void prep(
    const float* __restrict__ x,      // [B][T][DIM]
    const float* __restrict__ Wih,    // [DIM][G4]
    const float* __restrict__ Whh,    // [HID][G4]
    const float* __restrict__ bias,   // [G4] gate-major
    _Float16* __restrict__ x16,       // [B][T][DIM]
    _Float16* __restrict__ aXf,       // [8w][4j][4ks][64l][8i] scaled f16
    unsigned* __restrict__ whh_pk,    // [g*16+i][512 tid] scaled packed pairs
    float* __restrict__ bias_s)       // [512] ch=4u+g, scaled
{
    const size_t gtid   = (size_t)blockIdx.x * blockDim.x + threadIdx.x;
    const size_t stride = (size_t)gridDim.x * blockDim.x;

    const size_t n_x2 = (size_t)NBATCH * T_SEQ * DIM / 2;
    for (size_t i = gtid; i < n_x2; i += stride) {
        float2 v = reinterpret_cast<const float2*>(x)[i];
        h2v p; p.x = (_Float16)v.x; p.y = (_Float16)v.y;
        reinterpret_cast<h2v*>(x16)[i] = p;
    }
    // Wih fragments: 65536 f16
    for (size_t n = gtid; n < 65536; n += stride) {
        int i  = (int)n & 7;
        int l  = ((int)n >> 3) & 63;
        int ks = ((int)n >> 9) & 3;
        int j  = ((int)n >> 11) & 3;
        int w  = (int)n >> 13;
        int col = l & 15, hi = l >> 4;
        int chr  = 16 * (4 * w + j) + col;
        int wcol = (chr & 3) * HID + (chr >> 2);
        float sc = ((chr & 3) == 2) ? -2.0f * LOG2E : -LOG2E;
        int k = ks * 32 + hi * 8 + i;
        aXf[n] = (_Float16)(Wih[(size_t)k * G4 + wcol] * sc);
    }
    // Whh packed words: 32768
    for (size_t n = gtid; n < 32768; n += stride) {
        int tid = (int)n & 511;
        int gi  = (int)n >> 9;          // g*16+ii
        int g = gi >> 4, ii = gi & 15;
        int j = tid >> 2, q = tid & 3;
        int k0 = q * 32 + 2 * ii;
        float sc = (g == 2) ? -2.0f * LOG2E : -LOG2E;
        whh_pk[n] = pack2(Whh[(size_t)k0 * G4 + g * HID + j] * sc,
                          Whh[(size_t)(k0 + 1) * G4 + g * HID + j] * sc);
    }
    for (size_t n = gtid; n < 512; n += stride) {
        int gate = (int)n & 3, u = (int)n >> 2;
        float sc = (gate == 2) ? -2.0f * LOG2E : -LOG2E;
        bias_s[n] = bias[gate * HID + u] * sc;
    }
}

// ---- Phase 1 (MFMA): pre[lt][b][ch] = f16 of scaled pre-activation.
// A-fragments from prepacked aXf (16 coalesced b128). grid = (tc/TT)*4, 512 thr.
__global__ __launch_bounds__(512, 2) void pre_mfma(
    const _Float16* __restrict__ x16, // [B][T][DIM]
    const _Float16* __restrict__ aXf,
    const float* __restrict__ bias_s, // [512] scaled
    _Float16* __restrict__ pre,       // [tcnt][64][512] channel-interleaved, scaled
    int t0)
{
    const int tid = threadIdx.x;
    const int w   = tid >> 6;
    const int l   = tid & 63;
    const int col = l & 15;
    const int hi  = l >> 4;
    const int bg  = blockIdx.x & 3;
    const int lt0 = (blockIdx.x >> 2) * TT;
    const int batch = bg * 16 + col;

    f16x8 aX[4][4];
    f32x4 bv[4];
    #pragma unroll
    for (int j = 0; j < 4; ++j) {
        #pragma unroll
        for (int ks = 0; ks < 4; ++ks)
            aX[j][ks] = *reinterpret_cast<const f16x8*>(
                aXf + (((size_t)(w * 4 + j) * 4 + ks) << 9) + l * 8);
        bv[j] = *reinterpret_cast<const f32x4*>(bias_s + 64 * w + 16 * j + 4 * hi);
    }

    const _Float16* xb_base = x16 + (size_t)batch * T_SEQ * DIM + hi * 8;

    for (int tt = 0; tt < TT; ++tt) {
        const int lt = lt0 + tt;
        const int t  = t0 + lt;
        f16x8 xf[4];
        #pragma unroll
        for (int ks = 0; ks < 4; ++ks)
            xf[ks] = *reinterpret_cast<const f16x8*>(
                xb_base + (size_t)t * DIM + ks * 32);
        #pragma unroll
        for (int j = 0; j < 4; ++j) {
            f32x4 acc = bv[j];
            #pragma unroll
            for (int ks = 0; ks < 4; ++ks)
                acc = __builtin_amdgcn_mfma_f32_16x16x32_f16(aX[j][ks], xf[ks], acc, 0, 0, 0);
            uint2 o;
            o.x = pack2(acc[0], acc[1]);
            o.y = pack2(acc[2], acc[3]);
            *reinterpret_cast<uint2*>(
                pre + ((size_t)lt * NBATCH + batch) * G4 + 16 * (4 * w + j) + 4 * hi) = o;
        }
    }
}

// ---- Phase 2: scan (R12 proven body). grid.x = batch (64), block = 512:
// thread = (unit j=tid>>2, quarter q=tid&3). Weights/pre pre-scaled by -log2e
// (-2log2e for g): activation v = rcp(1+exp2(a)); tanh folded as 2v-1.
// state layout (floats): h[64*128] | c[64*128]
__global__ __launch_bounds__(512, 1) void lstm_scan(
    const _Float16* __restrict__ pre, // [tc][B][G4] channel-interleaved, scaled
    const unsigned* __restrict__ whh_pk, // [g*16+i][512]
    const float* __restrict__ h0,
    const float* __restrict__ c0,
    float* __restrict__ state,
    _Float16* __restrict__ trace,     // [B][T][HID]
    int t0, int tc)
{
    __shared__ __align__(16) _Float16 h_sh[2][HID];

    const int tid = threadIdx.x;
    const int j = tid >> 2;           // unit
    const int q = tid & 3;            // k-quarter / gate owner
    const int b = blockIdx.x;
    const bool q1 = (q & 1) != 0;
    const bool q2 = (q & 2) != 0;

    float* st_h = state;
    float* st_c = state + NBATCH * HID;

    // W_hh fragments from prepacked buffer: 64 coalesced loads
    unsigned wpk[4][16];
    #pragma unroll
    for (int g = 0; g < 4; ++g)
        #pragma unroll
        for (int ii = 0; ii < 16; ++ii)
            wpk[g][ii] = whh_pk[(size_t)(g * 16 + ii) * 512 + tid];

    float c, hj;
    if (t0 == 0) {
        hj = h0[b * HID + j]; c = c0[b * HID + j];
    } else {
        hj = st_h[b * HID + j];
        c  = st_c[b * HID + j];
    }
    if (q == 0) h_sh[0][j] = (_Float16)hj;

    const size_t pstep = (size_t)NBATCH * G4;
    const _Float16* pb = pre + (size_t)b * G4 + tid;
    _Float16* tb = trace + ((size_t)b * T_SEQ + t0) * HID + j;

    // prologue: load group 0
    unsigned short prA[GRP], prB[GRP];
    #pragma unroll
    for (int s = 0; s < GRP; ++s)
        prA[s] = __builtin_bit_cast(unsigned short, pb[(size_t)s * pstep]);

    __syncthreads();

#define LOADG(PR, TGN)                                                       \
    {                                                                        \
        const int tgl = (TGN);                                               \
        _Pragma("unroll")                                                    \
        for (int s = 0; s < GRP; ++s)                                        \
            PR[s] = __builtin_bit_cast(unsigned short,                       \
                        pb[(size_t)(tgl + s) * pstep]);                      \
    }

#define STEP16(PR, TG)                                                       \
    _Pragma("unroll")                                                        \
    for (int s = 0; s < GRP; ++s) {                                          \
        const int cur = s & 1;                                               \
        const uint4* hp = reinterpret_cast<const uint4*>(&h_sh[cur][q * 32]);\
        float a0 = 0.f, a1 = 0.f, a2 = 0.f, a3 = 0.f;                        \
        _Pragma("unroll")                                                    \
        for (int m = 0; m < 4; ++m) {                                        \
            uint4 hv = hp[m];                                                \
            a0 = dot2(hv.x, wpk[0][4 * m + 0], a0);                          \
            a1 = dot2(hv.x, wpk[1][4 * m + 0], a1);                          \
            a2 = dot2(hv.x, wpk[2][4 * m + 0], a2);                          \
            a3 = dot2(hv.x, wpk[3][4 * m + 0], a3);                          \
            a0 = dot2(hv.y, wpk[0][4 * m + 1], a0);                          \
            a1 = dot2(hv.y, wpk[1][4 * m + 1], a1);                          \
            a2 = dot2(hv.y, wpk[2][4 * m + 1], a2);                          \
            a3 = dot2(hv.y, wpk[3][4 * m + 1], a3);                          \
            a0 = dot2(hv.z, wpk[0][4 * m + 2], a0);                          \
            a1 = dot2(hv.z, wpk[1][4 * m + 2], a1);                          \
            a2 = dot2(hv.z, wpk[2][4 * m + 2], a2);                          \
            a3 = dot2(hv.z, wpk[3][4 * m + 2], a3);                          \
            a0 = dot2(hv.w, wpk[0][4 * m + 3], a0);                          \
            a1 = dot2(hv.w, wpk[1][4 * m + 3], a1);                          \
            a2 = dot2(hv.w, wpk[2][4 * m + 3], a2);                          \
            a3 = dot2(hv.w, wpk[3][4 * m + 3], a3);                          \
        }                                                                    \
        float t01  = q1 ? a1 : a0;                                           \
        float t01o = q1 ? a0 : a1;                                           \
        t01 += qmov<QP_XOR1>(t01o);                                          \
        float t23  = q1 ? a3 : a2;                                           \
        float t23o = q1 ? a2 : a3;                                           \
        t23 += qmov<QP_XOR1>(t23o);                                          \
        float tq  = q2 ? t23 : t01;                                          \
        float tqo = q2 ? t01 : t23;                                          \
        tq += qmov<QP_XOR2>(tqo);                                            \
        tq += (float)__builtin_bit_cast(_Float16, PR[s]);                    \
        float v = rcp_(1.0f + exp2_(tq));                                    \
        float gi = qmov<QP_B0>(v);                                           \
        float gf = qmov<QP_B1>(v);                                           \
        float vg = qmov<QP_B2>(v);                                           \
        float go = qmov<QP_B3>(v);                                           \
        c = fmaf(gf, c, fmaf(gi + gi, vg, -gi));                             \
        float vc = rcp_(1.0f + exp2_(-2.0f * LOG2E * c));                    \
        float hn = fmaf(go + go, vc, -go);                                   \
        hj = hn;                                                             \
        _Float16 h16 = (_Float16)hn;                                         \
        if (q == 0) {                                                        \
            h_sh[cur ^ 1][j] = h16;                                          \
            tb[(size_t)((TG) + s) * HID] = h16;                              \
        }                                                                    \
        barrier_lgkm();                                                      \
    }

    for (int tg = 0; tg < tc; tg += 2 * GRP) {
        LOADG(prB, tg + GRP);                            // next group (in range)
        STEP16(prA, tg);
        const int tga = (tg + 2 * GRP < tc) ? tg + 2 * GRP : tg;  // clamp
        LOADG(prA, tga);
        STEP16(prB, tg + GRP);
    }
#undef LOADG
#undef STEP16

    if (t0 + tc < T_SEQ) {
        if (q == 0) { st_h[b * HID + j] = hj; st_c[b * HID + j] = c; }
    }
}

// ---- Phase 3a: FC partials. grid (64, 4): block (b, ck) covers T/4 of the t-range.
__global__ __launch_bounds__(256) void fc_part(
    const _Float16* __restrict__ trace,  // [B][T][HID]
    const float* __restrict__ fcw,       // [2][T*HID]
    float* __restrict__ part)            // [B][4][2]
{
    __shared__ float red[4][2];
    const int b = blockIdx.x, ck = blockIdx.y, tid = threadIdx.x;
    const int n4 = T_SEQ * HID / 4;
    const int base = ck * n4;
    const _Float16* tbase = trace + (size_t)b * (T_SEQ * HID) + base;
    const float* w0 = fcw + base;
    const float* w1 = fcw + (size_t)T_SEQ * HID + base;

    float s0 = 0.f, s1 = 0.f;
    for (int i = tid * 8; i < n4; i += 256 * 8) {
        uint4 tv = *reinterpret_cast<const uint4*>(tbase + i);
        float wa0[8], wa1[8];
        *reinterpret_cast<float4*>(&wa0[0]) = *reinterpret_cast<const float4*>(w0 + i);
        *reinterpret_cast<float4*>(&wa0[4]) = *reinterpret_cast<const float4*>(w0 + i + 4);
        *reinterpret_cast<float4*>(&wa1[0]) = *reinterpret_cast<const float4*>(w1 + i);
        *reinterpret_cast<float4*>(&wa1[4]) = *reinterpret_cast<const float4*>(w1 + i + 4);
        const unsigned* tw = reinterpret_cast<const unsigned*>(&tv);
        #pragma unroll
        for (int e = 0; e < 4; ++e) {
            h2v hh = __builtin_bit_cast(h2v, tw[e]);
            float hx = (float)hh.x, hy = (float)hh.y;
            s0 = fmaf(hx, wa0[2 * e], s0);
            s0 = fmaf(hy, wa0[2 * e + 1], s0);
            s1 = fmaf(hx, wa1[2 * e], s1);
            s1 = fmaf(hy, wa1[2 * e + 1], s1);
        }
    }
    #pragma unroll
    for (int d = 32; d >= 1; d >>= 1) {
        s0 += __shfl_xor(s0, d);
        s1 += __shfl_xor(s1, d);
    }
    const int w = tid >> 6;
    if ((tid & 63) == 0) { red[w][0] = s0; red[w][1] = s1; }
    __syncthreads();
    if (tid < 2) {
        part[(b * 4 + ck) * 2 + tid] =
            red[0][tid] + red[1][tid] + red[2][tid] + red[3][tid];
    }
}

// ---- Phase 3b: finish ----
__global__ __launch_bounds__(128) void fc_fin(
    const float* __restrict__ part,      // [B][4][2]
    const float* __restrict__ fcb,
    float* __restrict__ out)             // [B][2]
{
    const int tid = threadIdx.x;
    const int b = tid >> 1, o = tid & 1;
    float v = part[(b * 4 + 0) * 2 + o] + part[(b * 4 + 1) * 2 + o]
            + part[(b * 4 + 2) * 2 + o] + part[(b * 4 + 3) * 2 + o];
    out[b * 2 + o] = v + fcb[o];
}

extern "C" void kernel_launch(void* const* d_in, const int* in_sizes, int n_in,
                              void* d_out, int out_size, void* d_ws, size_t ws_size,
                              hipStream_t stream) {
    const float* x    = (const float*)d_in[0];
    const float* h0   = (const float*)d_in[1];
    const float* c0   = (const float*)d_in[2];
    const float* Wih  = (const float*)d_in[3];
    const float* Whh  = (const float*)d_in[4];
    const float* bias = (const float*)d_in[5];
    const float* fcw  = (const float*)d_in[6];
    const float* fcb  = (const float*)d_in[7];
    float* out = (float*)d_out;

    // ws layout (bytes): x16 32MB | trace 32MB | state 64KB | part 2KB |
    //                    aXf 128KB | whh_pk 128KB | bias_s 2KB | pre (rest)
    char* wsb = (char*)d_ws;
    const size_t X = (size_t)NBATCH * T_SEQ * DIM * 2;
    _Float16* x16    = (_Float16*)wsb;
    _Float16* trace  = (_Float16*)(wsb + X);
    float*    state  = (float*)(wsb + 2 * X);
    float*    part   = (float*)(wsb + 2 * X + 65536);
    _Float16* aXf    = (_Float16*)(wsb + 2 * X + 65536 + 2048);
    unsigned* whh_pk = (unsigned*)(wsb + 2 * X + 65536 + 2048 + 131072);
    float*    bias_s = (float*)(wsb + 2 * X + 65536 + 2048 + 2 * 131072);
    _Float16* pre    = (_Float16*)(wsb + 2 * X + 65536 + 2048 + 2 * 131072 + 2048);

    const size_t head = 2 * X + 65536 + 2048 + 2 * 131072 + 2048;
    const size_t per_t_bytes = (size_t)NBATCH * G4 * sizeof(_Float16);
    size_t avail = (ws_size > head) ? ws_size - head : 0;
    int Tc = (int)(avail / per_t_bytes);
    Tc &= ~(2 * GRP - 1);           // multiple of 32 (ping-pong; TT=16 divides)
    if (Tc < 2 * GRP) Tc = 2 * GRP; // fallback (ws known >= ~200 MB from R12)
    if (Tc > T_SEQ) Tc = T_SEQ;

    prep<<<512, 256, 0, stream>>>(x, Wih, Whh, bias, x16, aXf, whh_pk, bias_s);
    for (int t0 = 0; t0 < T_SEQ; t0 += Tc) {
        int tc = (t0 + Tc <= T_SEQ) ? Tc : (T_SEQ - t0);   // multiple of 32
        pre_mfma<<<(tc / TT) * 4, 512, 0, stream>>>(x16, aXf, bias_s, pre, t0);
        lstm_scan<<<64, 512, 0, stream>>>(pre, whh_pk, h0, c0, state, trace, t0, tc);
    }
    fc_part<<<dim3(64, 4), 256, 0, stream>>>(trace, fcw, part);
    fc_fin<<<1, 128, 0, stream>>>(part, fcb, out);
}